// Round 2
// baseline (544.249 us; speedup 1.0000x reference)
//
#include <hip/hip_runtime.h>
#include <math.h>

#define NN   100000
#define NE   1600000
#define FIN  256
#define HID  64
#define NC   40
#define NBKT 391          // buckets of 256 nodes: bucket = dst >> 8
#define EPB  6250         // edges per phase-A block (256 * 6250 = NE exactly)
#define CAP  4608         // per-bucket capacity (mean 4092, sd 64 -> 8 sigma slack)
#define SL   ((size_t)NN * 16)   // elements per feature slice (16 feats/node)

typedef __attribute__((ext_vector_type(8))) short short8;
typedef __attribute__((ext_vector_type(4))) float float4v;

static __device__ __forceinline__ short f2bf(float f) {   // RNE f32 -> bf16 bits
    unsigned u = __float_as_uint(f);
    u += 0x7FFFu + ((u >> 16) & 1u);
    return (short)(u >> 16);
}
static __device__ __forceinline__ float bf2f(unsigned short b) {
    return __uint_as_float((unsigned)b << 16);
}

// ---------- W1 -> bf16, transposed to [n][k] ----------
__global__ __launch_bounds__(256) void w1cvt_k(const float* __restrict__ W1,
                                               short* __restrict__ w1t) {
    int t = blockIdx.x * 256 + threadIdx.x;   // 16384
    int k = t >> 6, n = t & 63;
    w1t[n * FIN + k] = f2bf(W1[k * HID + n]);
}

// ---------- phase A: partition edges into 391 coarse buckets ----------
__global__ __launch_bounds__(256) void phaseA_k(const int* __restrict__ src,
                                                const int* __restrict__ dst,
                                                const float* __restrict__ w,
                                                int* __restrict__ cursor,      // [NBKT*16]
                                                int2* __restrict__ bucketbuf) {
    __shared__ int  hist[NBKT];
    __shared__ int  sc[512];
    __shared__ int  loc_base[NBKT];
    __shared__ int  loc_cur[NBKT];
    __shared__ int  gb[NBKT];
    __shared__ int2 buf[EPB];          // 50 KB
    const int t  = threadIdx.x;
    const int e0 = blockIdx.x * EPB;

    for (int i = t; i < NBKT; i += 256) hist[i] = 0;
    __syncthreads();
    for (int i = t; i < EPB; i += 256) atomicAdd(&hist[dst[e0 + i] >> 8], 1);
    __syncthreads();
    sc[t]       = (t       < NBKT) ? hist[t]       : 0;
    sc[t + 256] = (t + 256 < NBKT) ? hist[t + 256] : 0;
    __syncthreads();
    for (int off = 1; off < 512; off <<= 1) {
        int a0 = (t >= off) ? sc[t - off] : 0;
        int a1 = sc[t + 256 - off];
        __syncthreads();
        sc[t] += a0; sc[t + 256] += a1;
        __syncthreads();
    }
    for (int i = t; i < NBKT; i += 256) {
        int base = sc[i] - hist[i];
        loc_base[i] = base;
        loc_cur[i]  = base;
        gb[i] = atomicAdd(&cursor[i * 16], hist[i]);
    }
    __syncthreads();
    for (int i = t; i < EPB; i += 256) {
        int e = e0 + i;
        int d = dst[e];
        int b = d >> 8;
        int p = atomicAdd(&loc_cur[b], 1);
        buf[p] = make_int2(src[e] | ((d & 255) << 17), __float_as_int(w[e]));
    }
    __syncthreads();
    for (int b = t; b < NBKT; b += 256) {
        int lb = loc_base[b], n = hist[b];
        int2* dstp = bucketbuf + (size_t)b * CAP + gb[b];
        for (int i = 0; i < n; ++i) dstp[i] = buf[lb + i];
    }
}

// ---------- scan of bucket counts -> bucket bases ----------
__global__ __launch_bounds__(512) void scanB_k(const int* __restrict__ cursor,
                                               int* __restrict__ bucketbase,
                                               int* __restrict__ row_start) {
    __shared__ int tmp[512];
    int t = threadIdx.x;
    int v = (t < NBKT) ? cursor[t * 16] : 0;
    tmp[t] = v;
    __syncthreads();
    for (int off = 1; off < 512; off <<= 1) {
        int add = (t >= off) ? tmp[t - off] : 0;
        __syncthreads(); tmp[t] += add; __syncthreads();
    }
    if (t < NBKT) bucketbase[t] = tmp[t] - v;
    if (t == 0) { bucketbase[NBKT] = NE; row_start[NN] = NE; }
}

// ---------- phase B: per-bucket CSR build + row_start + dinv ----------
__global__ __launch_bounds__(256) void phaseB_k(const int* __restrict__ bucketbase,
                                                const int2* __restrict__ bucketbuf,
                                                int2* __restrict__ e8,
                                                int* __restrict__ row_start,
                                                float* __restrict__ dinv) {
    __shared__ int2 buf[CAP];
    __shared__ int2 buf2[CAP];
    __shared__ int  hist2[256];
    __shared__ int  tmp[256];
    __shared__ int  base2[257];
    __shared__ int  cur2[256];
    const int b = blockIdx.x, t = threadIdx.x;
    const int g0   = bucketbase[b];
    const int cntb = bucketbase[b + 1] - g0;
    const int n0   = b * 256;
    const int nnb  = (NN - n0 < 256) ? (NN - n0) : 256;

    hist2[t] = 0;
    __syncthreads();
    const int2* bb = bucketbuf + (size_t)b * CAP;
    for (int i = t; i < cntb; i += 256) {
        int2 kv = bb[i];
        buf[i] = kv;
        atomicAdd(&hist2[kv.x >> 17], 1);
    }
    __syncthreads();
    int v = hist2[t];
    tmp[t] = v;
    __syncthreads();
    for (int off = 1; off < 256; off <<= 1) {
        int add = (t >= off) ? tmp[t - off] : 0;
        __syncthreads(); tmp[t] += add; __syncthreads();
    }
    int excl = tmp[t] - v;
    base2[t] = excl;
    cur2[t]  = excl;
    if (t == 0) base2[256] = cntb;
    if (t < nnb) row_start[n0 + t] = g0 + excl;
    __syncthreads();
    for (int i = t; i < cntb; i += 256) {
        int2 kv = buf[i];
        int d = kv.x >> 17;
        int p = atomicAdd(&cur2[d], 1);
        buf2[p] = make_int2(kv.x & 0x1FFFF, kv.y);
    }
    __syncthreads();
    for (int i = t; i < cntb; i += 256) e8[g0 + i] = buf2[i];
    if (t < nnb) {
        float s = 0.f;
        int j1 = base2[t + 1];
        for (int j = base2[t]; j < j1; ++j) s += __int_as_float(buf2[j].y);
        dinv[n0 + t] = rsqrtf(1.0f + s);
    }
}

// ---------- layer-1 GEMM via MFMA bf16, slice-major output: h1s[s][r][f] = bf16(dinv[r]*(x@W1)[r][16s+f]) ----------
__global__ __launch_bounds__(256) void gemm1_mfma_k(const float* __restrict__ x,
                                                    const short* __restrict__ w1t,  // bf16 [64][256]
                                                    const float* __restrict__ dinv,
                                                    unsigned short* __restrict__ h1) {
    const int wave = threadIdx.x >> 6;
    const int lane = threadIdx.x & 63;
    const int m    = lane & 15;
    const int quad = lane >> 4;
    const int r0   = blockIdx.x * 64 + wave * 16;
    const int row  = r0 + m;
    const int rcl  = (row < NN) ? row : (NN - 1);
    const float* xrow = x + (size_t)rcl * FIN + quad * 8;

    float4v acc0 = {0.f,0.f,0.f,0.f}, acc1 = acc0, acc2 = acc0, acc3 = acc0;

#pragma unroll
    for (int kc = 0; kc < 8; ++kc) {
        const int kof = kc * 32 + quad * 8;
        float4 xa = *(const float4*)(xrow + kc * 32);
        float4 xb = *(const float4*)(xrow + kc * 32 + 4);
        short8 a;
        a[0] = f2bf(xa.x); a[1] = f2bf(xa.y); a[2] = f2bf(xa.z); a[3] = f2bf(xa.w);
        a[4] = f2bf(xb.x); a[5] = f2bf(xb.y); a[6] = f2bf(xb.z); a[7] = f2bf(xb.w);
        short8 b0 = *(const short8*)(w1t + (0 * 16 + m) * FIN + kof);
        short8 b1 = *(const short8*)(w1t + (1 * 16 + m) * FIN + kof);
        short8 b2 = *(const short8*)(w1t + (2 * 16 + m) * FIN + kof);
        short8 b3 = *(const short8*)(w1t + (3 * 16 + m) * FIN + kof);
        acc0 = __builtin_amdgcn_mfma_f32_16x16x32_bf16(a, b0, acc0, 0, 0, 0);
        acc1 = __builtin_amdgcn_mfma_f32_16x16x32_bf16(a, b1, acc1, 0, 0, 0);
        acc2 = __builtin_amdgcn_mfma_f32_16x16x32_bf16(a, b2, acc2, 0, 0, 0);
        acc3 = __builtin_amdgcn_mfma_f32_16x16x32_bf16(a, b3, acc3, 0, 0, 0);
    }
    // C/D layout: col = lane&15, row = quad*4 + reg
#pragma unroll
    for (int r = 0; r < 4; ++r) {
        int rr = r0 + quad * 4 + r;
        if (rr < NN) {
            float dv = dinv[rr];
            size_t ro = (size_t)rr * 16 + m;
            h1[ro]          = (unsigned short)f2bf(acc0[r] * dv);
            h1[SL + ro]     = (unsigned short)f2bf(acc1[r] * dv);
            h1[2 * SL + ro] = (unsigned short)f2bf(acc2[r] * dv);
            h1[3 * SL + ro] = (unsigned short)f2bf(acc3[r] * dv);
        }
    }
}

// ---------- gatherA, feature-slice s: 8 edge-groups x 8 feat-lanes; slice table L2-resident ----------
// agg1 = dv*(sum w*h1'[s]) + dv*h1'[v]; emit Rp = bf16(dv*relu(agg1+b1)), slice-major
__global__ __launch_bounds__(256) void gatherAs_k(const int* __restrict__ row_start,
                                                  const int2* __restrict__ e8,
                                                  const float* __restrict__ dinv,
                                                  const unsigned short* __restrict__ h1, // [4][NN][16]
                                                  const float* __restrict__ b1,
                                                  unsigned short* __restrict__ Rp,       // [4][NN][16]
                                                  int s) {
    const int v    = blockIdx.x * 4 + (threadIdx.x >> 6);
    const int lane = threadIdx.x & 63;
    const int eg   = lane >> 3;          // edge group 0..7
    const int f    = lane & 7;           // dword index within slice (2 feats)
    const unsigned short* hs = h1 + (size_t)s * SL;
    const int i0 = row_start[v], i1 = row_start[v + 1];

    float a0 = 0.f, a1 = 0.f, c0 = 0.f, c1 = 0.f;
    int i = i0 + eg;
    for (; i + 8 < i1; i += 16) {        // 2 edges per group per iter (ILP)
        int2 ea = e8[i];
        int2 eb = e8[i + 8];
        unsigned pa = *(const unsigned*)(hs + (size_t)ea.x * 16 + f * 2);
        unsigned pb = *(const unsigned*)(hs + (size_t)eb.x * 16 + f * 2);
        float wa = __int_as_float(ea.y), wb = __int_as_float(eb.y);
        a0 = fmaf(__uint_as_float(pa << 16),          wa, a0);
        a1 = fmaf(__uint_as_float(pa & 0xFFFF0000u), wa, a1);
        c0 = fmaf(__uint_as_float(pb << 16),          wb, c0);
        c1 = fmaf(__uint_as_float(pb & 0xFFFF0000u), wb, c1);
    }
    if (i < i1) {
        int2 ea = e8[i];
        unsigned pa = *(const unsigned*)(hs + (size_t)ea.x * 16 + f * 2);
        float wa = __int_as_float(ea.y);
        a0 = fmaf(__uint_as_float(pa << 16),          wa, a0);
        a1 = fmaf(__uint_as_float(pa & 0xFFFF0000u), wa, a1);
    }
    a0 += c0; a1 += c1;
    a0 += __shfl_xor(a0, 8);  a1 += __shfl_xor(a1, 8);    // reduce over edge groups
    a0 += __shfl_xor(a0, 16); a1 += __shfl_xor(a1, 16);
    a0 += __shfl_xor(a0, 32); a1 += __shfl_xor(a1, 32);

    const float dv = dinv[v];
    unsigned ps = *(const unsigned*)(hs + (size_t)v * 16 + f * 2);
    float r0 = dv * (a0 + __uint_as_float(ps << 16));            // + self-loop
    float r1 = dv * (a1 + __uint_as_float(ps & 0xFFFF0000u));
    float2 bb = *(const float2*)(b1 + s * 16 + f * 2);
    r0 = fmaxf(r0 + bb.x, 0.f);                                  // relu(agg1 + b1)
    r1 = fmaxf(r1 + bb.y, 0.f);
    if (eg == 0) {
        unsigned pk = (unsigned)(unsigned short)f2bf(dv * r0)
                    | ((unsigned)(unsigned short)f2bf(dv * r1) << 16);
        *(unsigned*)(Rp + (size_t)s * SL + (size_t)v * 16 + f * 2) = pk;  // pre-scaled
    }
}

// ---------- gatherB, feature-slice s: agg2 = dv*(sum w*Rp[s]) + dv*Rp[v], slice-major ----------
__global__ __launch_bounds__(256) void gatherBs_k(const int* __restrict__ row_start,
                                                  const int2* __restrict__ e8,
                                                  const float* __restrict__ dinv,
                                                  const unsigned short* __restrict__ Rp, // [4][NN][16]
                                                  float* __restrict__ agg2,              // [4][NN][16]
                                                  int s) {
    const int v    = blockIdx.x * 4 + (threadIdx.x >> 6);
    const int lane = threadIdx.x & 63;
    const int eg   = lane >> 3;
    const int f    = lane & 7;
    const unsigned short* hs = Rp + (size_t)s * SL;
    const int i0 = row_start[v], i1 = row_start[v + 1];

    float a0 = 0.f, a1 = 0.f, c0 = 0.f, c1 = 0.f;
    int i = i0 + eg;
    for (; i + 8 < i1; i += 16) {
        int2 ea = e8[i];
        int2 eb = e8[i + 8];
        unsigned pa = *(const unsigned*)(hs + (size_t)ea.x * 16 + f * 2);
        unsigned pb = *(const unsigned*)(hs + (size_t)eb.x * 16 + f * 2);
        float wa = __int_as_float(ea.y), wb = __int_as_float(eb.y);
        a0 = fmaf(__uint_as_float(pa << 16),          wa, a0);
        a1 = fmaf(__uint_as_float(pa & 0xFFFF0000u), wa, a1);
        c0 = fmaf(__uint_as_float(pb << 16),          wb, c0);
        c1 = fmaf(__uint_as_float(pb & 0xFFFF0000u), wb, c1);
    }
    if (i < i1) {
        int2 ea = e8[i];
        unsigned pa = *(const unsigned*)(hs + (size_t)ea.x * 16 + f * 2);
        float wa = __int_as_float(ea.y);
        a0 = fmaf(__uint_as_float(pa << 16),          wa, a0);
        a1 = fmaf(__uint_as_float(pa & 0xFFFF0000u), wa, a1);
    }
    a0 += c0; a1 += c1;
    a0 += __shfl_xor(a0, 8);  a1 += __shfl_xor(a1, 8);
    a0 += __shfl_xor(a0, 16); a1 += __shfl_xor(a1, 16);
    a0 += __shfl_xor(a0, 32); a1 += __shfl_xor(a1, 32);

    const float dv = dinv[v];
    unsigned ps = *(const unsigned*)(hs + (size_t)v * 16 + f * 2);
    float r0 = dv * (a0 + __uint_as_float(ps << 16));
    float r1 = dv * (a1 + __uint_as_float(ps & 0xFFFF0000u));
    if (eg == 0)
        *(float2*)(agg2 + (size_t)s * SL + (size_t)v * 16 + f * 2) = make_float2(r0, r1);
}

// ---------- gemm3 + log_softmax: out = logsm(agg2 @ W2 + b2), thread per node; agg2 slice-major ----------
__global__ __launch_bounds__(256) void gemm3_logsm_k(const float* __restrict__ agg2,
                                                     const float* __restrict__ W2,
                                                     const float* __restrict__ b2,
                                                     float* __restrict__ out) {
    __shared__ float w2s[HID * NC];
    __shared__ float b2s[NC];
    for (int i = threadIdx.x; i < HID * NC; i += 256) w2s[i] = W2[i];
    if (threadIdx.x < NC) b2s[threadIdx.x] = b2[threadIdx.x];
    __syncthreads();

    const int r = blockIdx.x * 256 + threadIdx.x;
    if (r >= NN) return;
    float acc[NC];
#pragma unroll
    for (int c = 0; c < NC; ++c) acc[c] = b2s[c];

#pragma unroll
    for (int s = 0; s < 4; ++s) {
        const float* base = agg2 + (size_t)s * SL + (size_t)r * 16;
#pragma unroll
        for (int q = 0; q < 4; ++q) {
            float4 v = *(const float4*)(base + q * 4);
            const int kk = s * 16 + q * 4;
#pragma unroll
            for (int c = 0; c < NC; ++c) {
                acc[c] = fmaf(v.x, w2s[(kk + 0) * NC + c], acc[c]);
                acc[c] = fmaf(v.y, w2s[(kk + 1) * NC + c], acc[c]);
                acc[c] = fmaf(v.z, w2s[(kk + 2) * NC + c], acc[c]);
                acc[c] = fmaf(v.w, w2s[(kk + 3) * NC + c], acc[c]);
            }
        }
    }
    float m = acc[0];
#pragma unroll
    for (int c = 1; c < NC; ++c) m = fmaxf(m, acc[c]);
    float s = 0.f;
#pragma unroll
    for (int c = 0; c < NC; ++c) s += __expf(acc[c] - m);
    float lg = m + __logf(s);
    float* outp = out + (size_t)r * NC;
#pragma unroll
    for (int c = 0; c < NC; c += 4)
        *(float4*)&outp[c] = make_float4(acc[c] - lg, acc[c+1] - lg, acc[c+2] - lg, acc[c+3] - lg);
}

extern "C" void kernel_launch(void* const* d_in, const int* in_sizes, int n_in,
                              void* d_out, int out_size, void* d_ws, size_t ws_size,
                              hipStream_t stream) {
    const float* x  = (const float*)d_in[0];
    const int*   ei = (const int*)d_in[1];     // [2, E]: row0=src, row1=dst
    const float* ea = (const float*)d_in[2];
    const float* W1 = (const float*)d_in[3];
    const float* b1 = (const float*)d_in[4];
    const float* W2 = (const float*)d_in[5];
    const float* b2 = (const float*)d_in[6];
    const int* src = ei;
    const int* dst = ei + NE;
    float* out = (float*)d_out;

    char* ws = (char*)d_ws;
    float* dinv       = (float*)(ws + 0);            //    400,000 B
    int*   row_start  = (int*)  (ws + 400000);       //    400,016 B (NN+1)
    int*   cursor     = (int*)  (ws + 800016);       //     25,024 B (391*16, line-padded)
    int*   bucketbase = (int*)  (ws + 825040);       //      1,568 B
    int2*  e8         = (int2*) (ws + 826608);       // 12,800,000 B
    unsigned short* h1 = (unsigned short*)(ws + 13626608);   // 12,800,000 B (bf16, slice-major, dinv-prescaled)
    unsigned short* Rp = (unsigned short*)(ws + 26426608);   // 12,800,000 B (bf16, slice-major, dinv-prescaled)
    float* agg2       = (float*)(ws + 39226608);     // 25,600,000 B (slice-major)
    short* w1t        = (short*)(ws + 64826608);     //     32,768 B -> total 64.86 MB
    int2*  bucketbuf  = (int2*)agg2;                 // 14.4 MB, aliases agg2 (dead until gatherB)

    hipMemsetAsync(cursor, 0, 391 * 16 * sizeof(int), stream);

    w1cvt_k <<<64,   256, 0, stream>>>(W1, w1t);
    phaseA_k<<<256,  256, 0, stream>>>(src, dst, ea, cursor, bucketbuf);
    scanB_k <<<1,    512, 0, stream>>>(cursor, bucketbase, row_start);
    phaseB_k<<<NBKT, 256, 0, stream>>>(bucketbase, bucketbuf, e8, row_start, dinv);

    gemm1_mfma_k <<<(NN + 63) / 64, 256, 0, stream>>>(x, w1t, dinv, h1);
    for (int s = 0; s < 4; ++s)
        gatherAs_k<<<NN / 4, 256, 0, stream>>>(row_start, e8, dinv, h1, b1, Rp, s);
    for (int s = 0; s < 4; ++s)
        gatherBs_k<<<NN / 4, 256, 0, stream>>>(row_start, e8, dinv, Rp, agg2, s);
    gemm3_logsm_k<<<(NN + 255) / 256, 256, 0, stream>>>(agg2, W2, b2, out);
}

// Round 3
// 411.092 us; speedup vs baseline: 1.3239x; 1.3239x over previous
//
#include <hip/hip_runtime.h>
#include <math.h>

#define NN   100000
#define NE   1600000
#define FIN  256
#define HID  64
#define NC   40
#define NBKT 391          // buckets of 256 nodes: bucket = dst >> 8
#define EPB  6250         // edges per phase-A block (256 * 6250 = NE exactly)
#define CAP  4608         // per-bucket capacity (mean 4092, sd 64 -> 8 sigma slack)

typedef __attribute__((ext_vector_type(8))) short short8;
typedef __attribute__((ext_vector_type(4))) float float4v;

static __device__ __forceinline__ short f2bf(float f) {   // RNE f32 -> bf16 bits
    unsigned u = __float_as_uint(f);
    u += 0x7FFFu + ((u >> 16) & 1u);
    return (short)(u >> 16);
}
static __device__ __forceinline__ float bf2f(unsigned short b) {
    return __uint_as_float((unsigned)b << 16);
}

// ---------- W1 -> bf16, transposed to [n][k] ----------
__global__ __launch_bounds__(256) void w1cvt_k(const float* __restrict__ W1,
                                               short* __restrict__ w1t) {
    int t = blockIdx.x * 256 + threadIdx.x;   // 16384
    int k = t >> 6, n = t & 63;
    w1t[n * FIN + k] = f2bf(W1[k * HID + n]);
}

// ---------- phase A: partition edges into 391 coarse buckets ----------
__global__ __launch_bounds__(256) void phaseA_k(const int* __restrict__ src,
                                                const int* __restrict__ dst,
                                                const float* __restrict__ w,
                                                int* __restrict__ cursor,      // [NBKT*16]
                                                int2* __restrict__ bucketbuf) {
    __shared__ int  hist[NBKT];
    __shared__ int  sc[512];
    __shared__ int  loc_base[NBKT];
    __shared__ int  loc_cur[NBKT];
    __shared__ int  gb[NBKT];
    __shared__ int2 buf[EPB];          // 50 KB
    const int t  = threadIdx.x;
    const int e0 = blockIdx.x * EPB;

    for (int i = t; i < NBKT; i += 256) hist[i] = 0;
    __syncthreads();
    for (int i = t; i < EPB; i += 256) atomicAdd(&hist[dst[e0 + i] >> 8], 1);
    __syncthreads();
    sc[t]       = (t       < NBKT) ? hist[t]       : 0;
    sc[t + 256] = (t + 256 < NBKT) ? hist[t + 256] : 0;
    __syncthreads();
    for (int off = 1; off < 512; off <<= 1) {
        int a0 = (t >= off) ? sc[t - off] : 0;
        int a1 = sc[t + 256 - off];
        __syncthreads();
        sc[t] += a0; sc[t + 256] += a1;
        __syncthreads();
    }
    for (int i = t; i < NBKT; i += 256) {
        int base = sc[i] - hist[i];
        loc_base[i] = base;
        loc_cur[i]  = base;
        gb[i] = atomicAdd(&cursor[i * 16], hist[i]);
    }
    __syncthreads();
    for (int i = t; i < EPB; i += 256) {
        int e = e0 + i;
        int d = dst[e];
        int b = d >> 8;
        int p = atomicAdd(&loc_cur[b], 1);
        buf[p] = make_int2(src[e] | ((d & 255) << 17), __float_as_int(w[e]));
    }
    __syncthreads();
    for (int b = t; b < NBKT; b += 256) {
        int lb = loc_base[b], n = hist[b];
        int2* dstp = bucketbuf + (size_t)b * CAP + gb[b];
        for (int i = 0; i < n; ++i) dstp[i] = buf[lb + i];
    }
}

// ---------- scan of bucket counts -> bucket bases ----------
__global__ __launch_bounds__(512) void scanB_k(const int* __restrict__ cursor,
                                               int* __restrict__ bucketbase,
                                               int* __restrict__ row_start) {
    __shared__ int tmp[512];
    int t = threadIdx.x;
    int v = (t < NBKT) ? cursor[t * 16] : 0;
    tmp[t] = v;
    __syncthreads();
    for (int off = 1; off < 512; off <<= 1) {
        int add = (t >= off) ? tmp[t - off] : 0;
        __syncthreads(); tmp[t] += add; __syncthreads();
    }
    if (t < NBKT) bucketbase[t] = tmp[t] - v;
    if (t == 0) { bucketbase[NBKT] = NE; row_start[NN] = NE; }
}

// ---------- phase B: per-bucket CSR build + row_start + dinv ----------
__global__ __launch_bounds__(256) void phaseB_k(const int* __restrict__ bucketbase,
                                                const int2* __restrict__ bucketbuf,
                                                int2* __restrict__ e8,
                                                int* __restrict__ row_start,
                                                float* __restrict__ dinv) {
    __shared__ int2 buf[CAP];
    __shared__ int2 buf2[CAP];
    __shared__ int  hist2[256];
    __shared__ int  tmp[256];
    __shared__ int  base2[257];
    __shared__ int  cur2[256];
    const int b = blockIdx.x, t = threadIdx.x;
    const int g0   = bucketbase[b];
    const int cntb = bucketbase[b + 1] - g0;
    const int n0   = b * 256;
    const int nnb  = (NN - n0 < 256) ? (NN - n0) : 256;

    hist2[t] = 0;
    __syncthreads();
    const int2* bb = bucketbuf + (size_t)b * CAP;
    for (int i = t; i < cntb; i += 256) {
        int2 kv = bb[i];
        buf[i] = kv;
        atomicAdd(&hist2[kv.x >> 17], 1);
    }
    __syncthreads();
    int v = hist2[t];
    tmp[t] = v;
    __syncthreads();
    for (int off = 1; off < 256; off <<= 1) {
        int add = (t >= off) ? tmp[t - off] : 0;
        __syncthreads(); tmp[t] += add; __syncthreads();
    }
    int excl = tmp[t] - v;
    base2[t] = excl;
    cur2[t]  = excl;
    if (t == 0) base2[256] = cntb;
    if (t < nnb) row_start[n0 + t] = g0 + excl;
    __syncthreads();
    for (int i = t; i < cntb; i += 256) {
        int2 kv = buf[i];
        int d = kv.x >> 17;
        int p = atomicAdd(&cur2[d], 1);
        buf2[p] = make_int2(kv.x & 0x1FFFF, kv.y);
    }
    __syncthreads();
    for (int i = t; i < cntb; i += 256) e8[g0 + i] = buf2[i];
    if (t < nnb) {
        float s = 0.f;
        int j1 = base2[t + 1];
        for (int j = base2[t]; j < j1; ++j) s += __int_as_float(buf2[j].y);
        dinv[n0 + t] = rsqrtf(1.0f + s);
    }
}

// ---------- layer-1 GEMM via MFMA bf16, pre-scaled: h1'[r] = bf16(dinv[r] * (x@W1)[r]) ----------
// MLP fix: prefetch the lane's full 64-float row segment (16 float4 loads in flight, was 2).
__global__ __launch_bounds__(256) void gemm1_mfma_k(const float* __restrict__ x,
                                                    const short* __restrict__ w1t,  // bf16 [64][256]
                                                    const float* __restrict__ dinv,
                                                    unsigned short* __restrict__ h1) {
    const int wave = threadIdx.x >> 6;
    const int lane = threadIdx.x & 63;
    const int m    = lane & 15;
    const int quad = lane >> 4;
    const int r0   = blockIdx.x * 64 + wave * 16;
    const int row  = r0 + m;
    const int rcl  = (row < NN) ? row : (NN - 1);
    const float* xrow = x + (size_t)rcl * FIN + quad * 8;

    float4 xv[16];
#pragma unroll
    for (int kc = 0; kc < 8; ++kc) {
        xv[2 * kc]     = *(const float4*)(xrow + kc * 32);
        xv[2 * kc + 1] = *(const float4*)(xrow + kc * 32 + 4);
    }

    float4v acc0 = {0.f,0.f,0.f,0.f}, acc1 = acc0, acc2 = acc0, acc3 = acc0;

#pragma unroll
    for (int kc = 0; kc < 8; ++kc) {
        const int kof = kc * 32 + quad * 8;
        float4 xa = xv[2 * kc];
        float4 xb = xv[2 * kc + 1];
        short8 a;
        a[0] = f2bf(xa.x); a[1] = f2bf(xa.y); a[2] = f2bf(xa.z); a[3] = f2bf(xa.w);
        a[4] = f2bf(xb.x); a[5] = f2bf(xb.y); a[6] = f2bf(xb.z); a[7] = f2bf(xb.w);
        short8 b0 = *(const short8*)(w1t + (0 * 16 + m) * FIN + kof);
        short8 b1 = *(const short8*)(w1t + (1 * 16 + m) * FIN + kof);
        short8 b2 = *(const short8*)(w1t + (2 * 16 + m) * FIN + kof);
        short8 b3 = *(const short8*)(w1t + (3 * 16 + m) * FIN + kof);
        acc0 = __builtin_amdgcn_mfma_f32_16x16x32_bf16(a, b0, acc0, 0, 0, 0);
        acc1 = __builtin_amdgcn_mfma_f32_16x16x32_bf16(a, b1, acc1, 0, 0, 0);
        acc2 = __builtin_amdgcn_mfma_f32_16x16x32_bf16(a, b2, acc2, 0, 0, 0);
        acc3 = __builtin_amdgcn_mfma_f32_16x16x32_bf16(a, b3, acc3, 0, 0, 0);
    }
    // C/D layout: col = lane&15, row = quad*4 + reg
#pragma unroll
    for (int r = 0; r < 4; ++r) {
        int rr = r0 + quad * 4 + r;
        if (rr < NN) {
            float dv = dinv[rr];
            unsigned short* hp = h1 + (size_t)rr * HID + m;
            hp[0]  = (unsigned short)f2bf(acc0[r] * dv);
            hp[16] = (unsigned short)f2bf(acc1[r] * dv);
            hp[32] = (unsigned short)f2bf(acc2[r] * dv);
            hp[48] = (unsigned short)f2bf(acc3[r] * dv);
        }
    }
}

// ---------- gatherA: dword-packed (2 bf16 features/lane, wave halves split edges) ----------
// agg1 = dv*(sum w*h1'[s]) + dv*h1'[v]; emit R' = bf16(dv*relu(agg1+b1))
__global__ __launch_bounds__(256) void gatherA_k(const int* __restrict__ row_start,
                                                 const int2* __restrict__ e8,
                                                 const float* __restrict__ dinv,
                                                 const unsigned short* __restrict__ h,
                                                 const float* __restrict__ b1,
                                                 unsigned short* __restrict__ Rp) {
    const int v    = blockIdx.x * 4 + (threadIdx.x >> 6);
    const int lane = threadIdx.x & 63;
    const int half = lane >> 5;          // 0: even edges, 1: odd edges
    const int fp2  = (lane & 31) << 1;   // feature pair base (0,2,...,62)
    const int i0 = row_start[v], i1 = row_start[v + 1];

    float a0 = 0.f, a1 = 0.f, c0 = 0.f, c1 = 0.f;
    int i = i0 + half;
    for (; i + 2 < i1; i += 4) {         // this half: edges i and i+2
        int2 ea = e8[i];
        int2 eb = e8[i + 2];
        unsigned pa = *(const unsigned*)(h + (size_t)ea.x * HID + fp2);
        unsigned pb = *(const unsigned*)(h + (size_t)eb.x * HID + fp2);
        float wa = __int_as_float(ea.y), wb = __int_as_float(eb.y);
        a0 = fmaf(__uint_as_float(pa << 16),          wa, a0);
        a1 = fmaf(__uint_as_float(pa & 0xFFFF0000u), wa, a1);
        c0 = fmaf(__uint_as_float(pb << 16),          wb, c0);
        c1 = fmaf(__uint_as_float(pb & 0xFFFF0000u), wb, c1);
    }
    if (i < i1) {
        int2 ea = e8[i];
        unsigned pa = *(const unsigned*)(h + (size_t)ea.x * HID + fp2);
        float wa = __int_as_float(ea.y);
        a0 = fmaf(__uint_as_float(pa << 16),          wa, a0);
        a1 = fmaf(__uint_as_float(pa & 0xFFFF0000u), wa, a1);
    }
    a0 += c0; a1 += c1;
    a0 += __shfl_xor(a0, 32);            // merge the two halves
    a1 += __shfl_xor(a1, 32);

    const float dv = dinv[v];
    unsigned ps = *(const unsigned*)(h + (size_t)v * HID + fp2);
    float r0 = dv * (a0 + __uint_as_float(ps << 16));           // + self-loop
    float r1 = dv * (a1 + __uint_as_float(ps & 0xFFFF0000u));
    r0 = fmaxf(r0 + b1[fp2],     0.f);                          // relu(agg1 + b1)
    r1 = fmaxf(r1 + b1[fp2 + 1], 0.f);
    if (half == 0) {
        unsigned pk = (unsigned)(unsigned short)f2bf(dv * r0)
                    | ((unsigned)(unsigned short)f2bf(dv * r1) << 16);
        *(unsigned*)(Rp + (size_t)v * HID + fp2) = pk;          // pre-scaled for gatherB
    }
}

// ---------- gatherB: dword-packed; agg2 = dv*(sum w*R'[s]) + dv*R'[v] ----------
__global__ __launch_bounds__(256) void gatherB_k(const int* __restrict__ row_start,
                                                 const int2* __restrict__ e8,
                                                 const float* __restrict__ dinv,
                                                 const unsigned short* __restrict__ Rp,
                                                 float* __restrict__ agg2) {
    const int v    = blockIdx.x * 4 + (threadIdx.x >> 6);
    const int lane = threadIdx.x & 63;
    const int half = lane >> 5;
    const int fp2  = (lane & 31) << 1;
    const int i0 = row_start[v], i1 = row_start[v + 1];

    float a0 = 0.f, a1 = 0.f, c0 = 0.f, c1 = 0.f;
    int i = i0 + half;
    for (; i + 2 < i1; i += 4) {
        int2 ea = e8[i];
        int2 eb = e8[i + 2];
        unsigned pa = *(const unsigned*)(Rp + (size_t)ea.x * HID + fp2);
        unsigned pb = *(const unsigned*)(Rp + (size_t)eb.x * HID + fp2);
        float wa = __int_as_float(ea.y), wb = __int_as_float(eb.y);
        a0 = fmaf(__uint_as_float(pa << 16),          wa, a0);
        a1 = fmaf(__uint_as_float(pa & 0xFFFF0000u), wa, a1);
        c0 = fmaf(__uint_as_float(pb << 16),          wb, c0);
        c1 = fmaf(__uint_as_float(pb & 0xFFFF0000u), wb, c1);
    }
    if (i < i1) {
        int2 ea = e8[i];
        unsigned pa = *(const unsigned*)(Rp + (size_t)ea.x * HID + fp2);
        float wa = __int_as_float(ea.y);
        a0 = fmaf(__uint_as_float(pa << 16),          wa, a0);
        a1 = fmaf(__uint_as_float(pa & 0xFFFF0000u), wa, a1);
    }
    a0 += c0; a1 += c1;
    a0 += __shfl_xor(a0, 32);
    a1 += __shfl_xor(a1, 32);

    const float dv = dinv[v];
    unsigned ps = *(const unsigned*)(Rp + (size_t)v * HID + fp2);
    float r0 = dv * (a0 + __uint_as_float(ps << 16));
    float r1 = dv * (a1 + __uint_as_float(ps & 0xFFFF0000u));
    if (half == 0)
        *(float2*)(agg2 + (size_t)v * HID + fp2) = make_float2(r0, r1);
}

// ---------- gemm3 + log_softmax: out = logsm(agg2 @ W2 + b2), thread per node ----------
__global__ __launch_bounds__(256) void gemm3_logsm_k(const float* __restrict__ agg2,
                                                     const float* __restrict__ W2,
                                                     const float* __restrict__ b2,
                                                     float* __restrict__ out) {
    __shared__ float w2s[HID * NC];
    __shared__ float b2s[NC];
    for (int i = threadIdx.x; i < HID * NC; i += 256) w2s[i] = W2[i];
    if (threadIdx.x < NC) b2s[threadIdx.x] = b2[threadIdx.x];
    __syncthreads();

    const int r = blockIdx.x * 256 + threadIdx.x;
    if (r >= NN) return;
    float acc[NC];
#pragma unroll
    for (int c = 0; c < NC; ++c) acc[c] = b2s[c];

    const float4* row4 = (const float4*)(agg2 + (size_t)r * HID);
    for (int kk = 0; kk < HID; kk += 4) {
        float4 v = row4[kk >> 2];
#pragma unroll
        for (int c = 0; c < NC; ++c) {
            acc[c] = fmaf(v.x, w2s[(kk + 0) * NC + c], acc[c]);
            acc[c] = fmaf(v.y, w2s[(kk + 1) * NC + c], acc[c]);
            acc[c] = fmaf(v.z, w2s[(kk + 2) * NC + c], acc[c]);
            acc[c] = fmaf(v.w, w2s[(kk + 3) * NC + c], acc[c]);
        }
    }
    float m = acc[0];
#pragma unroll
    for (int c = 1; c < NC; ++c) m = fmaxf(m, acc[c]);
    float s = 0.f;
#pragma unroll
    for (int c = 0; c < NC; ++c) s += __expf(acc[c] - m);
    float lg = m + __logf(s);
    float* outp = out + (size_t)r * NC;
#pragma unroll
    for (int c = 0; c < NC; c += 4)
        *(float4*)&outp[c] = make_float4(acc[c] - lg, acc[c+1] - lg, acc[c+2] - lg, acc[c+3] - lg);
}

extern "C" void kernel_launch(void* const* d_in, const int* in_sizes, int n_in,
                              void* d_out, int out_size, void* d_ws, size_t ws_size,
                              hipStream_t stream) {
    const float* x  = (const float*)d_in[0];
    const int*   ei = (const int*)d_in[1];     // [2, E]: row0=src, row1=dst
    const float* ea = (const float*)d_in[2];
    const float* W1 = (const float*)d_in[3];
    const float* b1 = (const float*)d_in[4];
    const float* W2 = (const float*)d_in[5];
    const float* b2 = (const float*)d_in[6];
    const int* src = ei;
    const int* dst = ei + NE;
    float* out = (float*)d_out;

    char* ws = (char*)d_ws;
    float* dinv       = (float*)(ws + 0);            //    400,000 B
    int*   row_start  = (int*)  (ws + 400000);       //    400,016 B (NN+1)
    int*   cursor     = (int*)  (ws + 800016);       //     25,024 B (391*16, line-padded)
    int*   bucketbase = (int*)  (ws + 825040);       //      1,568 B
    int2*  e8         = (int2*) (ws + 826608);       // 12,800,000 B
    unsigned short* h1 = (unsigned short*)(ws + 13626608);   // 12,800,000 B (bf16, dinv-prescaled)
    unsigned short* Rp = (unsigned short*)(ws + 26426608);   // 12,800,000 B (bf16, dinv-prescaled)
    float* agg2       = (float*)(ws + 39226608);     // 25,600,000 B
    short* w1t        = (short*)(ws + 64826608);     //     32,768 B -> total 64.86 MB
    int2*  bucketbuf  = (int2*)agg2;                 // 14.4 MB, aliases agg2 (dead until gatherB)

    hipMemsetAsync(cursor, 0, 391 * 16 * sizeof(int), stream);

    w1cvt_k <<<64,   256, 0, stream>>>(W1, w1t);
    phaseA_k<<<256,  256, 0, stream>>>(src, dst, ea, cursor, bucketbuf);
    scanB_k <<<1,    512, 0, stream>>>(cursor, bucketbase, row_start);
    phaseB_k<<<NBKT, 256, 0, stream>>>(bucketbase, bucketbuf, e8, row_start, dinv);

    gemm1_mfma_k <<<(NN + 63) / 64, 256, 0, stream>>>(x, w1t, dinv, h1);
    gatherA_k    <<<NN / 4, 256, 0, stream>>>(row_start, e8, dinv, h1, b1, Rp);
    gatherB_k    <<<NN / 4, 256, 0, stream>>>(row_start, e8, dinv, Rp, agg2);
    gemm3_logsm_k<<<(NN + 255) / 256, 256, 0, stream>>>(agg2, W2, b2, out);
}

// Round 4
// 379.335 us; speedup vs baseline: 1.4347x; 1.0837x over previous
//
#include <hip/hip_runtime.h>
#include <math.h>

#define NN   100000
#define NE   1600000
#define FIN  256
#define HID  64
#define NC   40
#define NBKT 391          // buckets of 256 nodes: bucket = dst >> 8
#define EPB  6250         // edges per phase-A block (256 * 6250 = NE exactly)
#define CAP  4608         // per-bucket capacity (mean 4092, sd 64 -> 8 sigma slack)

typedef __attribute__((ext_vector_type(8))) short short8;
typedef __attribute__((ext_vector_type(4))) float float4v;

static __device__ __forceinline__ short f2bf(float f) {   // RNE f32 -> bf16 bits
    unsigned u = __float_as_uint(f);
    u += 0x7FFFu + ((u >> 16) & 1u);
    return (short)(u >> 16);
}
static __device__ __forceinline__ float bf2f(unsigned short b) {
    return __uint_as_float((unsigned)b << 16);
}

// ---------- W1 -> bf16, transposed to [n][k] ----------
__global__ __launch_bounds__(256) void w1cvt_k(const float* __restrict__ W1,
                                               short* __restrict__ w1t) {
    int t = blockIdx.x * 256 + threadIdx.x;   // 16384
    int k = t >> 6, n = t & 63;
    w1t[n * FIN + k] = f2bf(W1[k * HID + n]);
}

// ---------- phase A: partition edges into 391 coarse buckets ----------
__global__ __launch_bounds__(256) void phaseA_k(const int* __restrict__ src,
                                                const int* __restrict__ dst,
                                                const float* __restrict__ w,
                                                int* __restrict__ cursor,      // [NBKT*16]
                                                int2* __restrict__ bucketbuf) {
    __shared__ int  hist[NBKT];
    __shared__ int  sc[512];
    __shared__ int  loc_base[NBKT];
    __shared__ int  loc_cur[NBKT];
    __shared__ int  gb[NBKT];
    __shared__ int2 buf[EPB];          // 50 KB
    const int t  = threadIdx.x;
    const int e0 = blockIdx.x * EPB;

    for (int i = t; i < NBKT; i += 256) hist[i] = 0;
    __syncthreads();
    for (int i = t; i < EPB; i += 256) atomicAdd(&hist[dst[e0 + i] >> 8], 1);
    __syncthreads();
    sc[t]       = (t       < NBKT) ? hist[t]       : 0;
    sc[t + 256] = (t + 256 < NBKT) ? hist[t + 256] : 0;
    __syncthreads();
    for (int off = 1; off < 512; off <<= 1) {
        int a0 = (t >= off) ? sc[t - off] : 0;
        int a1 = sc[t + 256 - off];
        __syncthreads();
        sc[t] += a0; sc[t + 256] += a1;
        __syncthreads();
    }
    for (int i = t; i < NBKT; i += 256) {
        int base = sc[i] - hist[i];
        loc_base[i] = base;
        loc_cur[i]  = base;
        gb[i] = atomicAdd(&cursor[i * 16], hist[i]);
    }
    __syncthreads();
    for (int i = t; i < EPB; i += 256) {
        int e = e0 + i;
        int d = dst[e];
        int b = d >> 8;
        int p = atomicAdd(&loc_cur[b], 1);
        buf[p] = make_int2(src[e] | ((d & 255) << 17), __float_as_int(w[e]));
    }
    __syncthreads();
    for (int b = t; b < NBKT; b += 256) {
        int lb = loc_base[b], n = hist[b];
        int2* dstp = bucketbuf + (size_t)b * CAP + gb[b];
        for (int i = 0; i < n; ++i) dstp[i] = buf[lb + i];
    }
}

// ---------- scan of bucket counts -> bucket bases ----------
__global__ __launch_bounds__(512) void scanB_k(const int* __restrict__ cursor,
                                               int* __restrict__ bucketbase,
                                               int* __restrict__ row_start) {
    __shared__ int tmp[512];
    int t = threadIdx.x;
    int v = (t < NBKT) ? cursor[t * 16] : 0;
    tmp[t] = v;
    __syncthreads();
    for (int off = 1; off < 512; off <<= 1) {
        int add = (t >= off) ? tmp[t - off] : 0;
        __syncthreads(); tmp[t] += add; __syncthreads();
    }
    if (t < NBKT) bucketbase[t] = tmp[t] - v;
    if (t == 0) { bucketbase[NBKT] = NE; row_start[NN] = NE; }
}

// ---------- phase B: per-bucket CSR build + row_start + dinv ----------
__global__ __launch_bounds__(256) void phaseB_k(const int* __restrict__ bucketbase,
                                                const int2* __restrict__ bucketbuf,
                                                int2* __restrict__ e8,
                                                int* __restrict__ row_start,
                                                float* __restrict__ dinv) {
    __shared__ int2 buf[CAP];
    __shared__ int2 buf2[CAP];
    __shared__ int  hist2[256];
    __shared__ int  tmp[256];
    __shared__ int  base2[257];
    __shared__ int  cur2[256];
    const int b = blockIdx.x, t = threadIdx.x;
    const int g0   = bucketbase[b];
    const int cntb = bucketbase[b + 1] - g0;
    const int n0   = b * 256;
    const int nnb  = (NN - n0 < 256) ? (NN - n0) : 256;

    hist2[t] = 0;
    __syncthreads();
    const int2* bb = bucketbuf + (size_t)b * CAP;
    for (int i = t; i < cntb; i += 256) {
        int2 kv = bb[i];
        buf[i] = kv;
        atomicAdd(&hist2[kv.x >> 17], 1);
    }
    __syncthreads();
    int v = hist2[t];
    tmp[t] = v;
    __syncthreads();
    for (int off = 1; off < 256; off <<= 1) {
        int add = (t >= off) ? tmp[t - off] : 0;
        __syncthreads(); tmp[t] += add; __syncthreads();
    }
    int excl = tmp[t] - v;
    base2[t] = excl;
    cur2[t]  = excl;
    if (t == 0) base2[256] = cntb;
    if (t < nnb) row_start[n0 + t] = g0 + excl;
    __syncthreads();
    for (int i = t; i < cntb; i += 256) {
        int2 kv = buf[i];
        int d = kv.x >> 17;
        int p = atomicAdd(&cur2[d], 1);
        buf2[p] = make_int2(kv.x & 0x1FFFF, kv.y);
    }
    __syncthreads();
    for (int i = t; i < cntb; i += 256) e8[g0 + i] = buf2[i];
    if (t < nnb) {
        float s = 0.f;
        int j1 = base2[t + 1];
        for (int j = base2[t]; j < j1; ++j) s += __int_as_float(buf2[j].y);
        dinv[n0 + t] = rsqrtf(1.0f + s);
    }
}

// ---------- layer-1 GEMM via MFMA bf16, pre-scaled: h1'[r] = bf16(dinv[r] * (x@W1)[r]) ----------
// 16 float4 x-loads forced in flight before the MFMA loop (asm memory barrier stops re-sinking).
__global__ __launch_bounds__(256) void gemm1_mfma_k(const float* __restrict__ x,
                                                    const short* __restrict__ w1t,  // bf16 [64][256]
                                                    const float* __restrict__ dinv,
                                                    unsigned short* __restrict__ h1) {
    const int wave = threadIdx.x >> 6;
    const int lane = threadIdx.x & 63;
    const int m    = lane & 15;
    const int quad = lane >> 4;
    const int r0   = blockIdx.x * 64 + wave * 16;
    const int row  = r0 + m;
    const int rcl  = (row < NN) ? row : (NN - 1);
    const float* xrow = x + (size_t)rcl * FIN + quad * 8;

    float4 xv[16];
#pragma unroll
    for (int kc = 0; kc < 8; ++kc) {
        xv[2 * kc]     = *(const float4*)(xrow + kc * 32);
        xv[2 * kc + 1] = *(const float4*)(xrow + kc * 32 + 4);
    }
    asm volatile("" ::: "memory");   // keep all 16 loads issued before compute

    float4v acc0 = {0.f,0.f,0.f,0.f}, acc1 = acc0, acc2 = acc0, acc3 = acc0;

#pragma unroll
    for (int kc = 0; kc < 8; ++kc) {
        const int kof = kc * 32 + quad * 8;
        float4 xa = xv[2 * kc];
        float4 xb = xv[2 * kc + 1];
        short8 a;
        a[0] = f2bf(xa.x); a[1] = f2bf(xa.y); a[2] = f2bf(xa.z); a[3] = f2bf(xa.w);
        a[4] = f2bf(xb.x); a[5] = f2bf(xb.y); a[6] = f2bf(xb.z); a[7] = f2bf(xb.w);
        short8 b0 = *(const short8*)(w1t + (0 * 16 + m) * FIN + kof);
        short8 b1 = *(const short8*)(w1t + (1 * 16 + m) * FIN + kof);
        short8 b2 = *(const short8*)(w1t + (2 * 16 + m) * FIN + kof);
        short8 b3 = *(const short8*)(w1t + (3 * 16 + m) * FIN + kof);
        acc0 = __builtin_amdgcn_mfma_f32_16x16x32_bf16(a, b0, acc0, 0, 0, 0);
        acc1 = __builtin_amdgcn_mfma_f32_16x16x32_bf16(a, b1, acc1, 0, 0, 0);
        acc2 = __builtin_amdgcn_mfma_f32_16x16x32_bf16(a, b2, acc2, 0, 0, 0);
        acc3 = __builtin_amdgcn_mfma_f32_16x16x32_bf16(a, b3, acc3, 0, 0, 0);
    }
    // C/D layout: col = lane&15, row = quad*4 + reg
#pragma unroll
    for (int r = 0; r < 4; ++r) {
        int rr = r0 + quad * 4 + r;
        if (rr < NN) {
            float dv = dinv[rr];
            unsigned short* hp = h1 + (size_t)rr * HID + m;
            hp[0]  = (unsigned short)f2bf(acc0[r] * dv);
            hp[16] = (unsigned short)f2bf(acc1[r] * dv);
            hp[32] = (unsigned short)f2bf(acc2[r] * dv);
            hp[48] = (unsigned short)f2bf(acc3[r] * dv);
        }
    }
}

// ---------- gatherA: 8 edge-slots x 8 feat-lanes (uint4 = 8 bf16), 2-deep unroll ----------
// agg1 = dv*(sum w*h1'[s]) + dv*h1'[v]; emit R' = bf16(dv*relu(agg1+b1))
__global__ __launch_bounds__(256) void gatherA_k(const int* __restrict__ row_start,
                                                 const int2* __restrict__ e8,
                                                 const float* __restrict__ dinv,
                                                 const unsigned short* __restrict__ h,
                                                 const float* __restrict__ b1,
                                                 unsigned short* __restrict__ Rp) {
    const int v    = blockIdx.x * 4 + (threadIdx.x >> 6);
    const int lane = threadIdx.x & 63;
    const int slot = lane >> 3;          // edge slot 0..7
    const int fg   = lane & 7;           // feature group: 8 bf16 = 16 B
    const int i0 = row_start[v], i1 = row_start[v + 1];

    float acc[8] = {0.f,0.f,0.f,0.f,0.f,0.f,0.f,0.f};
    for (int i = i0; i < i1; i += 16) {   // 16 edges per iter -> 16 gathers in flight
        int iiA = i + slot, iiB = i + 8 + slot;
        bool okA = iiA < i1, okB = iiB < i1;
        int2 eA = e8[okA ? iiA : (NE - 1)];
        int2 eB = e8[okB ? iiB : (NE - 1)];
        int  sA = okA ? eA.x : 0;         // OOB slots gather hot row 0, weight 0
        int  sB = okB ? eB.x : 0;
        float wA = okA ? __int_as_float(eA.y) : 0.f;
        float wB = okB ? __int_as_float(eB.y) : 0.f;
        uint4 pA = *(const uint4*)(h + (size_t)sA * HID + fg * 8);
        uint4 pB = *(const uint4*)(h + (size_t)sB * HID + fg * 8);
        acc[0] = fmaf(__uint_as_float(pA.x << 16),         wA, acc[0]);
        acc[1] = fmaf(__uint_as_float(pA.x & 0xFFFF0000u), wA, acc[1]);
        acc[2] = fmaf(__uint_as_float(pA.y << 16),         wA, acc[2]);
        acc[3] = fmaf(__uint_as_float(pA.y & 0xFFFF0000u), wA, acc[3]);
        acc[4] = fmaf(__uint_as_float(pA.z << 16),         wA, acc[4]);
        acc[5] = fmaf(__uint_as_float(pA.z & 0xFFFF0000u), wA, acc[5]);
        acc[6] = fmaf(__uint_as_float(pA.w << 16),         wA, acc[6]);
        acc[7] = fmaf(__uint_as_float(pA.w & 0xFFFF0000u), wA, acc[7]);
        acc[0] = fmaf(__uint_as_float(pB.x << 16),         wB, acc[0]);
        acc[1] = fmaf(__uint_as_float(pB.x & 0xFFFF0000u), wB, acc[1]);
        acc[2] = fmaf(__uint_as_float(pB.y << 16),         wB, acc[2]);
        acc[3] = fmaf(__uint_as_float(pB.y & 0xFFFF0000u), wB, acc[3]);
        acc[4] = fmaf(__uint_as_float(pB.z << 16),         wB, acc[4]);
        acc[5] = fmaf(__uint_as_float(pB.z & 0xFFFF0000u), wB, acc[5]);
        acc[6] = fmaf(__uint_as_float(pB.w << 16),         wB, acc[6]);
        acc[7] = fmaf(__uint_as_float(pB.w & 0xFFFF0000u), wB, acc[7]);
    }
#pragma unroll
    for (int mk = 8; mk <= 32; mk <<= 1) {
#pragma unroll
        for (int q = 0; q < 8; ++q) acc[q] += __shfl_xor(acc[q], mk);
    }

    const float dv = dinv[v];
    uint4 ps = *(const uint4*)(h + (size_t)v * HID + fg * 8);   // self-loop row
    float4 bA = *(const float4*)(b1 + fg * 8);
    float4 bB = *(const float4*)(b1 + fg * 8 + 4);
    float r0 = fmaxf(dv * (acc[0] + __uint_as_float(ps.x << 16))         + bA.x, 0.f);
    float r1 = fmaxf(dv * (acc[1] + __uint_as_float(ps.x & 0xFFFF0000u)) + bA.y, 0.f);
    float r2 = fmaxf(dv * (acc[2] + __uint_as_float(ps.y << 16))         + bA.z, 0.f);
    float r3 = fmaxf(dv * (acc[3] + __uint_as_float(ps.y & 0xFFFF0000u)) + bA.w, 0.f);
    float r4 = fmaxf(dv * (acc[4] + __uint_as_float(ps.z << 16))         + bB.x, 0.f);
    float r5 = fmaxf(dv * (acc[5] + __uint_as_float(ps.z & 0xFFFF0000u)) + bB.y, 0.f);
    float r6 = fmaxf(dv * (acc[6] + __uint_as_float(ps.w << 16))         + bB.z, 0.f);
    float r7 = fmaxf(dv * (acc[7] + __uint_as_float(ps.w & 0xFFFF0000u)) + bB.w, 0.f);
    if (slot == 0) {
        uint4 pk;
        pk.x = (unsigned)(unsigned short)f2bf(dv * r0) | ((unsigned)(unsigned short)f2bf(dv * r1) << 16);
        pk.y = (unsigned)(unsigned short)f2bf(dv * r2) | ((unsigned)(unsigned short)f2bf(dv * r3) << 16);
        pk.z = (unsigned)(unsigned short)f2bf(dv * r4) | ((unsigned)(unsigned short)f2bf(dv * r5) << 16);
        pk.w = (unsigned)(unsigned short)f2bf(dv * r6) | ((unsigned)(unsigned short)f2bf(dv * r7) << 16);
        *(uint4*)(Rp + (size_t)v * HID + fg * 8) = pk;          // pre-scaled for gatherB
    }
}

// ---------- gatherB: same structure; agg2 = dv*(sum w*R'[s]) + dv*R'[v] ----------
__global__ __launch_bounds__(256) void gatherB_k(const int* __restrict__ row_start,
                                                 const int2* __restrict__ e8,
                                                 const float* __restrict__ dinv,
                                                 const unsigned short* __restrict__ Rp,
                                                 float* __restrict__ agg2) {
    const int v    = blockIdx.x * 4 + (threadIdx.x >> 6);
    const int lane = threadIdx.x & 63;
    const int slot = lane >> 3;
    const int fg   = lane & 7;
    const int i0 = row_start[v], i1 = row_start[v + 1];

    float acc[8] = {0.f,0.f,0.f,0.f,0.f,0.f,0.f,0.f};
    for (int i = i0; i < i1; i += 16) {
        int iiA = i + slot, iiB = i + 8 + slot;
        bool okA = iiA < i1, okB = iiB < i1;
        int2 eA = e8[okA ? iiA : (NE - 1)];
        int2 eB = e8[okB ? iiB : (NE - 1)];
        int  sA = okA ? eA.x : 0;
        int  sB = okB ? eB.x : 0;
        float wA = okA ? __int_as_float(eA.y) : 0.f;
        float wB = okB ? __int_as_float(eB.y) : 0.f;
        uint4 pA = *(const uint4*)(Rp + (size_t)sA * HID + fg * 8);
        uint4 pB = *(const uint4*)(Rp + (size_t)sB * HID + fg * 8);
        acc[0] = fmaf(__uint_as_float(pA.x << 16),         wA, acc[0]);
        acc[1] = fmaf(__uint_as_float(pA.x & 0xFFFF0000u), wA, acc[1]);
        acc[2] = fmaf(__uint_as_float(pA.y << 16),         wA, acc[2]);
        acc[3] = fmaf(__uint_as_float(pA.y & 0xFFFF0000u), wA, acc[3]);
        acc[4] = fmaf(__uint_as_float(pA.z << 16),         wA, acc[4]);
        acc[5] = fmaf(__uint_as_float(pA.z & 0xFFFF0000u), wA, acc[5]);
        acc[6] = fmaf(__uint_as_float(pA.w << 16),         wA, acc[6]);
        acc[7] = fmaf(__uint_as_float(pA.w & 0xFFFF0000u), wA, acc[7]);
        acc[0] = fmaf(__uint_as_float(pB.x << 16),         wB, acc[0]);
        acc[1] = fmaf(__uint_as_float(pB.x & 0xFFFF0000u), wB, acc[1]);
        acc[2] = fmaf(__uint_as_float(pB.y << 16),         wB, acc[2]);
        acc[3] = fmaf(__uint_as_float(pB.y & 0xFFFF0000u), wB, acc[3]);
        acc[4] = fmaf(__uint_as_float(pB.z << 16),         wB, acc[4]);
        acc[5] = fmaf(__uint_as_float(pB.z & 0xFFFF0000u), wB, acc[5]);
        acc[6] = fmaf(__uint_as_float(pB.w << 16),         wB, acc[6]);
        acc[7] = fmaf(__uint_as_float(pB.w & 0xFFFF0000u), wB, acc[7]);
    }
#pragma unroll
    for (int mk = 8; mk <= 32; mk <<= 1) {
#pragma unroll
        for (int q = 0; q < 8; ++q) acc[q] += __shfl_xor(acc[q], mk);
    }

    const float dv = dinv[v];
    uint4 ps = *(const uint4*)(Rp + (size_t)v * HID + fg * 8);
    if (slot == 0) {
        float4 oA, oB;
        oA.x = dv * (acc[0] + __uint_as_float(ps.x << 16));
        oA.y = dv * (acc[1] + __uint_as_float(ps.x & 0xFFFF0000u));
        oA.z = dv * (acc[2] + __uint_as_float(ps.y << 16));
        oA.w = dv * (acc[3] + __uint_as_float(ps.y & 0xFFFF0000u));
        oB.x = dv * (acc[4] + __uint_as_float(ps.z << 16));
        oB.y = dv * (acc[5] + __uint_as_float(ps.z & 0xFFFF0000u));
        oB.z = dv * (acc[6] + __uint_as_float(ps.w << 16));
        oB.w = dv * (acc[7] + __uint_as_float(ps.w & 0xFFFF0000u));
        *(float4*)(agg2 + (size_t)v * HID + fg * 8)     = oA;
        *(float4*)(agg2 + (size_t)v * HID + fg * 8 + 4) = oB;
    }
}

// ---------- gemm3 + log_softmax: out = logsm(agg2 @ W2 + b2), thread per node ----------
__global__ __launch_bounds__(256) void gemm3_logsm_k(const float* __restrict__ agg2,
                                                     const float* __restrict__ W2,
                                                     const float* __restrict__ b2,
                                                     float* __restrict__ out) {
    __shared__ float w2s[HID * NC];
    __shared__ float b2s[NC];
    for (int i = threadIdx.x; i < HID * NC; i += 256) w2s[i] = W2[i];
    if (threadIdx.x < NC) b2s[threadIdx.x] = b2[threadIdx.x];
    __syncthreads();

    const int r = blockIdx.x * 256 + threadIdx.x;
    if (r >= NN) return;
    float acc[NC];
#pragma unroll
    for (int c = 0; c < NC; ++c) acc[c] = b2s[c];

    const float4* row4 = (const float4*)(agg2 + (size_t)r * HID);
    for (int kk = 0; kk < HID; kk += 4) {
        float4 v = row4[kk >> 2];
#pragma unroll
        for (int c = 0; c < NC; ++c) {
            acc[c] = fmaf(v.x, w2s[(kk + 0) * NC + c], acc[c]);
            acc[c] = fmaf(v.y, w2s[(kk + 1) * NC + c], acc[c]);
            acc[c] = fmaf(v.z, w2s[(kk + 2) * NC + c], acc[c]);
            acc[c] = fmaf(v.w, w2s[(kk + 3) * NC + c], acc[c]);
        }
    }
    float m = acc[0];
#pragma unroll
    for (int c = 1; c < NC; ++c) m = fmaxf(m, acc[c]);
    float s = 0.f;
#pragma unroll
    for (int c = 0; c < NC; ++c) s += __expf(acc[c] - m);
    float lg = m + __logf(s);
    float* outp = out + (size_t)r * NC;
#pragma unroll
    for (int c = 0; c < NC; c += 4)
        *(float4*)&outp[c] = make_float4(acc[c] - lg, acc[c+1] - lg, acc[c+2] - lg, acc[c+3] - lg);
}

extern "C" void kernel_launch(void* const* d_in, const int* in_sizes, int n_in,
                              void* d_out, int out_size, void* d_ws, size_t ws_size,
                              hipStream_t stream) {
    const float* x  = (const float*)d_in[0];
    const int*   ei = (const int*)d_in[1];     // [2, E]: row0=src, row1=dst
    const float* ea = (const float*)d_in[2];
    const float* W1 = (const float*)d_in[3];
    const float* b1 = (const float*)d_in[4];
    const float* W2 = (const float*)d_in[5];
    const float* b2 = (const float*)d_in[6];
    const int* src = ei;
    const int* dst = ei + NE;
    float* out = (float*)d_out;

    char* ws = (char*)d_ws;
    float* dinv       = (float*)(ws + 0);            //    400,000 B
    int*   row_start  = (int*)  (ws + 400000);       //    400,016 B (NN+1)
    int*   cursor     = (int*)  (ws + 800016);       //     25,024 B (391*16, line-padded)
    int*   bucketbase = (int*)  (ws + 825040);       //      1,568 B
    int2*  e8         = (int2*) (ws + 826608);       // 12,800,000 B
    unsigned short* h1 = (unsigned short*)(ws + 13626608);   // 12,800,000 B (bf16, dinv-prescaled)
    unsigned short* Rp = (unsigned short*)(ws + 26426608);   // 12,800,000 B (bf16, dinv-prescaled)
    float* agg2       = (float*)(ws + 39226608);     // 25,600,000 B
    short* w1t        = (short*)(ws + 64826608);     //     32,768 B -> total 64.86 MB
    int2*  bucketbuf  = (int2*)agg2;                 // 14.4 MB, aliases agg2 (dead until gatherB)

    hipMemsetAsync(cursor, 0, 391 * 16 * sizeof(int), stream);

    w1cvt_k <<<64,   256, 0, stream>>>(W1, w1t);
    phaseA_k<<<256,  256, 0, stream>>>(src, dst, ea, cursor, bucketbuf);
    scanB_k <<<1,    512, 0, stream>>>(cursor, bucketbase, row_start);
    phaseB_k<<<NBKT, 256, 0, stream>>>(bucketbase, bucketbuf, e8, row_start, dinv);

    gemm1_mfma_k <<<(NN + 63) / 64, 256, 0, stream>>>(x, w1t, dinv, h1);
    gatherA_k    <<<NN / 4, 256, 0, stream>>>(row_start, e8, dinv, h1, b1, Rp);
    gatherB_k    <<<NN / 4, 256, 0, stream>>>(row_start, e8, dinv, Rp, agg2);
    gemm3_logsm_k<<<(NN + 255) / 256, 256, 0, stream>>>(agg2, W2, b2, out);
}